// Round 1
// baseline (3280.627 us; speedup 1.0000x reference)
//
#include <hip/hip_runtime.h>

// LSTM H=512, B=256, T=256, D_IN=10, C=10. fp32 in/out.
// Strategy: recurrent GEMM via bf16 hi/lo split MFMA (3 terms => ~fp32 precision).
// Stacked gate weights row-interleaved (row = 4*i + gate) so each lane's 4 acc
// regs of mfma_f32_16x16x32_bf16 are {g,i,f,o} of one (h-row, col) -> fully
// lane-local LSTM cell update. One kernel launch per timestep (graph-captured).

#define Hdim 512
#define Bdim 256
#define Tdim 256
#define Kpad 544   // 512 (h) + 32 (x padded: 10 real + 22 zero)

typedef __bf16 bf16x8 __attribute__((ext_vector_type(8)));
typedef float f32x4 __attribute__((ext_vector_type(4)));

__device__ __forceinline__ unsigned short f2bf(float f) {
    union { float f; unsigned u; } x; x.f = f;
    unsigned r = x.u + 0x7FFFu + ((x.u >> 16) & 1u);
    return (unsigned short)(r >> 16);
}
__device__ __forceinline__ float bf2f(unsigned short h) {
    union { unsigned u; float f; } x; x.u = ((unsigned)h) << 16;
    return x.f;
}
__device__ __forceinline__ bf16x8 ld8(const unsigned short* p) {
    return *reinterpret_cast<const bf16x8*>(p);
}
__device__ __forceinline__ f32x4 mfma16(bf16x8 a, bf16x8 b, f32x4 c) {
    return __builtin_amdgcn_mfma_f32_16x16x32_bf16(a, b, c, 0, 0, 0);
}
__device__ __forceinline__ float sigm(float x) {
    return 1.f / (1.f + __expf(-x));
}
__device__ __forceinline__ float tanh_fast(float x) {
    // tanh(x) = 2/(1+exp(-2x)) - 1 ; saturates correctly at +-inf
    return 2.f / (1.f + __expf(-2.f * x)) - 1.f;
}

// ---------- prep: stacked gate weights -> bf16 hi/lo, row = 4*i + gate ----------
__global__ void k_prep_w(const float* __restrict__ w_gh, const float* __restrict__ w_ih,
                         const float* __restrict__ w_fh, const float* __restrict__ w_oh,
                         const float* __restrict__ w_gx, const float* __restrict__ w_ix,
                         const float* __restrict__ w_fx, const float* __restrict__ w_ox,
                         unsigned short* __restrict__ Whi, unsigned short* __restrict__ Wlo) {
    int idx = blockIdx.x * 256 + threadIdx.x;
    if (idx >= 2048 * Kpad) return;
    int rw = idx / Kpad;
    int k  = idx % Kpad;
    int gate = rw & 3;
    int i = rw >> 2;
    float v = 0.f;
    if (k < 512) {
        const float* wh = (gate == 0) ? w_gh : (gate == 1) ? w_ih : (gate == 2) ? w_fh : w_oh;
        v = wh[i * 512 + k];
    } else if (k < 522) {
        const float* wx = (gate == 0) ? w_gx : (gate == 1) ? w_ix : (gate == 2) ? w_fx : w_ox;
        v = wx[i * 10 + (k - 512)];
    }
    unsigned short hi = f2bf(v);
    unsigned short lo = f2bf(v - bf2f(hi));
    Whi[idx] = hi;
    Wlo[idx] = lo;
}

// ---------- prep: x -> Xhi/Xlo [t][b][32] (10 real cols, 22 zeros) ----------
__global__ void k_prep_x(const float* __restrict__ x,
                         unsigned short* __restrict__ Xhi, unsigned short* __restrict__ Xlo) {
    int idx = blockIdx.x * 256 + threadIdx.x;  // t*256*32 + b*32 + j
    if (idx >= Tdim * Bdim * 32) return;
    int j = idx & 31;
    int b = (idx >> 5) & 255;
    int t = idx >> 13;
    float v = 0.f;
    if (j < 10) v = x[(b * Tdim + t) * 10 + j];
    unsigned short hi = f2bf(v);
    unsigned short lo = f2bf(v - bf2f(hi));
    Xhi[idx] = hi;
    Xlo[idx] = lo;
}

__global__ void k_zero(float* __restrict__ p) {
    p[blockIdx.x * 256 + threadIdx.x] = 0.f;
}

// ---------- one LSTM timestep ----------
// grid 256 WGs x 256 thr. WG tile: 64 stacked rows x 32 cols. 4 waves, each 16x32.
__global__ __launch_bounds__(256) void k_step(
    const unsigned short* __restrict__ Whi, const unsigned short* __restrict__ Wlo,
    const unsigned short* __restrict__ Xhi, const unsigned short* __restrict__ Xlo,
    const unsigned short* __restrict__ Hr_hi, const unsigned short* __restrict__ Hr_lo,
    unsigned short* __restrict__ Hw_hi, unsigned short* __restrict__ Hw_lo,
    float* __restrict__ Cst, float* __restrict__ Hf32,
    const float* __restrict__ bg, const float* __restrict__ bi,
    const float* __restrict__ bf_, const float* __restrict__ bo,
    int t, int writeF32) {
    int bid = blockIdx.x;
    int m0  = (bid >> 3) * 64;     // stacked-row base
    int bn0 = (bid & 7) * 32;      // col base
    int lane = threadIdx.x & 63;
    int wv   = threadIdx.x >> 6;
    int lr = lane & 15;
    int q  = lane >> 4;
    int r  = m0 + wv * 16 + lr;    // A row this lane loads
    int kb_lane = q * 8;
    int i = (m0 >> 2) + wv * 4 + q;  // h-row this lane owns in epilogue

    float bgv = bg[i], biv = bi[i], bfv = bf_[i], bov = bo[i];
    f32x4 acc0, acc1;
    acc0[0] = bgv; acc0[1] = biv; acc0[2] = bfv; acc0[3] = bov;
    acc1 = acc0;

    const unsigned short* Ah = Whi + (size_t)r * Kpad;
    const unsigned short* Al = Wlo + (size_t)r * Kpad;
    int col0 = bn0 + lr;
    int col1 = col0 + 16;
    const unsigned short* Xb = Xhi + ((size_t)t * Bdim) * 32;
    const unsigned short* Xbl = Xlo + ((size_t)t * Bdim) * 32;

#pragma unroll
    for (int kb = 0; kb < 17; ++kb) {
        int k = kb * 32 + kb_lane;
        bf16x8 ahi = ld8(Ah + k);
        bf16x8 alo = ld8(Al + k);
        bf16x8 b0h, b0l, b1h, b1l;
        if (kb < 16) {
            b0h = ld8(Hr_hi + col0 * 512 + k);
            b0l = ld8(Hr_lo + col0 * 512 + k);
            b1h = ld8(Hr_hi + col1 * 512 + k);
            b1l = ld8(Hr_lo + col1 * 512 + k);
        } else {
            b0h = ld8(Xb  + col0 * 32 + kb_lane);
            b0l = ld8(Xbl + col0 * 32 + kb_lane);
            b1h = ld8(Xb  + col1 * 32 + kb_lane);
            b1l = ld8(Xbl + col1 * 32 + kb_lane);
        }
        acc0 = mfma16(ahi, b0h, acc0);
        acc0 = mfma16(ahi, b0l, acc0);
        acc0 = mfma16(alo, b0h, acc0);
        acc1 = mfma16(ahi, b1h, acc1);
        acc1 = mfma16(ahi, b1l, acc1);
        acc1 = mfma16(alo, b1h, acc1);
    }

    // epilogue: lane-local LSTM cell update for (i, col0) and (i, col1)
    {
        float g = tanh_fast(acc0[0]);
        float ii = sigm(acc0[1]);
        float f = sigm(acc0[2]);
        float o = sigm(acc0[3]);
        int idx = col0 * 512 + i;
        float cn = g * ii + Cst[idx] * f;
        float h = tanh_fast(cn) * o;
        Cst[idx] = cn;
        unsigned short hh = f2bf(h);
        Hw_hi[idx] = hh;
        Hw_lo[idx] = f2bf(h - bf2f(hh));
        if (writeF32) Hf32[idx] = h;
    }
    {
        float g = tanh_fast(acc1[0]);
        float ii = sigm(acc1[1]);
        float f = sigm(acc1[2]);
        float o = sigm(acc1[3]);
        int idx = col1 * 512 + i;
        float cn = g * ii + Cst[idx] * f;
        float h = tanh_fast(cn) * o;
        Cst[idx] = cn;
        unsigned short hh = f2bf(h);
        Hw_hi[idx] = hh;
        Hw_lo[idx] = f2bf(h - bf2f(hh));
        if (writeF32) Hf32[idx] = h;
    }
}

// ---------- output: logits + softmax ----------
__global__ void k_out(const float* __restrict__ Hf32, const float* __restrict__ w_out,
                      const float* __restrict__ b_out, float* __restrict__ out) {
    int b = blockIdx.x * 64 + threadIdx.x;  // 0..255
    const float* h = Hf32 + (size_t)b * 512;
    float logit[10];
#pragma unroll
    for (int c = 0; c < 10; ++c) {
        const float* wr = w_out + c * 512;
        float s = 0.f;
        for (int k = 0; k < 512; ++k) s += wr[k] * h[k];
        logit[c] = s + b_out[c];
    }
    float m = logit[0];
#pragma unroll
    for (int c = 1; c < 10; ++c) m = fmaxf(m, logit[c]);
    float e[10], sum = 0.f;
#pragma unroll
    for (int c = 0; c < 10; ++c) { e[c] = __expf(logit[c] - m); sum += e[c]; }
    float inv = 1.f / sum;
#pragma unroll
    for (int c = 0; c < 10; ++c) out[b * 10 + c] = e[c] * inv;
}

extern "C" void kernel_launch(void* const* d_in, const int* in_sizes, int n_in,
                              void* d_out, int out_size, void* d_ws, size_t ws_size,
                              hipStream_t stream) {
    const float* x    = (const float*)d_in[0];
    const float* w_gx = (const float*)d_in[1];
    const float* w_gh = (const float*)d_in[2];
    const float* b_g  = (const float*)d_in[3];
    const float* w_ix = (const float*)d_in[4];
    const float* w_ih = (const float*)d_in[5];
    const float* b_i  = (const float*)d_in[6];
    const float* w_fx = (const float*)d_in[7];
    const float* w_fh = (const float*)d_in[8];
    const float* b_f  = (const float*)d_in[9];
    const float* w_ox = (const float*)d_in[10];
    const float* w_oh = (const float*)d_in[11];
    const float* b_o  = (const float*)d_in[12];
    const float* w_out = (const float*)d_in[13];
    const float* b_out = (const float*)d_in[14];
    float* out = (float*)d_out;

    char* ws = (char*)d_ws;
    size_t off = 0;
    auto alloc = [&](size_t bytes) { void* p = ws + off; off += (bytes + 255) & ~255ull; return p; };
    unsigned short* Whi = (unsigned short*)alloc(2048ull * Kpad * 2);
    unsigned short* Wlo = (unsigned short*)alloc(2048ull * Kpad * 2);
    unsigned short* Xhi = (unsigned short*)alloc((size_t)Tdim * Bdim * 32 * 2);
    unsigned short* Xlo = (unsigned short*)alloc((size_t)Tdim * Bdim * 32 * 2);
    // the next three must stay contiguous for the single zero kernel:
    unsigned short* Hhi0 = (unsigned short*)alloc((size_t)Bdim * 512 * 2);
    unsigned short* Hlo0 = (unsigned short*)alloc((size_t)Bdim * 512 * 2);
    float* Cst = (float*)alloc((size_t)Bdim * 512 * 4);
    unsigned short* Hhi1 = (unsigned short*)alloc((size_t)Bdim * 512 * 2);
    unsigned short* Hlo1 = (unsigned short*)alloc((size_t)Bdim * 512 * 2);
    float* Hf32 = (float*)alloc((size_t)Bdim * 512 * 4);
    (void)ws_size; (void)in_sizes; (void)n_in; (void)out_size;

    // 1) prep weights (2048*544 elems)
    k_prep_w<<<(2048 * Kpad + 255) / 256, 256, 0, stream>>>(
        w_gh, w_ih, w_fh, w_oh, w_gx, w_ix, w_fx, w_ox, Whi, Wlo);
    // 2) prep x
    k_prep_x<<<(Tdim * Bdim * 32 + 255) / 256, 256, 0, stream>>>(x, Xhi, Xlo);
    // 3) zero Hhi0|Hlo0|Cst (contiguous 1 MiB = 262144 floats)
    k_zero<<<1024, 256, 0, stream>>>((float*)Hhi0);

    // 4) 256 timesteps
    for (int t = 0; t < Tdim; ++t) {
        const unsigned short* Rh = (t & 1) ? Hhi1 : Hhi0;
        const unsigned short* Rl = (t & 1) ? Hlo1 : Hlo0;
        unsigned short* Wh = (t & 1) ? Hhi0 : Hhi1;
        unsigned short* Wl = (t & 1) ? Hlo0 : Hlo1;
        k_step<<<256, 256, 0, stream>>>(Whi, Wlo, Xhi, Xlo, Rh, Rl, Wh, Wl,
                                        Cst, Hf32, b_g, b_i, b_f, b_o, t, t == Tdim - 1);
    }

    // 5) output
    k_out<<<4, 64, 0, stream>>>(Hf32, w_out, b_out, out);
}